// Round 11
// baseline (1349.359 us; speedup 1.0000x reference)
//
#include <hip/hip_runtime.h>

#define HID 51
#define TLEN 1024
#define NBATCH 4
#define NW 14             // 13 compute waves + 1 out wave
#define NTH (NW * 64)

typedef __attribute__((ext_vector_type(8))) short bf16x8;
typedef __attribute__((ext_vector_type(4))) float f32x4;

#define LOG2E 1.4426950408889634f

__device__ __forceinline__ float frcp(float v){ return __builtin_amdgcn_rcpf(v); }
// input already scaled by log2e (or 2*log2e for tanh-gate)
__device__ __forceinline__ float sigm2(float v){ return frcp(1.f + __builtin_amdgcn_exp2f(-v)); }
__device__ __forceinline__ float tanh_c(float c){   // c in true domain
    return fmaf(2.f, frcp(1.f + __builtin_amdgcn_exp2f(-2.f*LOG2E*c)), -1.f);
}
__device__ __forceinline__ unsigned short f2bf(float f){
    unsigned u = __float_as_uint(f);
    return (unsigned short)((u + 0x7FFFu + ((u>>16)&1u)) >> 16);   // RNE f32->bf16
}
__device__ __forceinline__ float bf2f(unsigned short b){ return __uint_as_float(((unsigned)b)<<16); }
__device__ __forceinline__ unsigned cvt1bf(float f){
    unsigned r; asm("v_cvt_pk_bf16_f32 %0, %1, 0" : "=v"(r) : "v"(f)); return r;
}

// LDS h layout = MFMA B-fragment-linear (validated R4): lane l reads 16B at
// short-index kb*512 + l*8 covering k = 32*kb + 8*(l>>4) + 0..7, col = l&15.
// Writer (unit j, col n): short-index = (j>>5)*512 + (n + ((j>>3)&3)*16)*8 + (j&7).
// N-packing: col 0-3 = h_hi(batch n), col 4-7 = h_lo(batch n-4), col 8-15 = h_hi dup.
// MFMA(W_hi,B) + MFMA(W_lo,B) yield all 3 hi/lo products; recombine:
//   pre = C1 + shfl_xor(C1,4) + shfl_xor(C2,8)   (bias/x only in cols 0-3)

__global__ __launch_bounds__(NTH)
void lstm2_mfma(const float* __restrict__ x,
                const float* __restrict__ W_ih0, const float* __restrict__ W_hh0,
                const float* __restrict__ b_ih0, const float* __restrict__ b_hh0,
                const float* __restrict__ W_ih1, const float* __restrict__ W_hh1,
                const float* __restrict__ b_ih1, const float* __restrict__ b_hh1,
                const float* __restrict__ W_lin, const float* __restrict__ b_lin,
                float* __restrict__ out)
{
    const int tid = threadIdx.x;
    const int w = tid >> 6;          // wave 0..13; waves 0..12 compute tile m=w
    const int l = tid & 63;          // lane
    const int n = l & 15;            // column slot
    const int p = l >> 4;            // lane group 0..3
    const int m = w;                 // M-tile id
    const bool cw = (m < 13);        // compute wave?

    __shared__ __align__(16) short H0[2][1024];   // packed hi/lo in columns
    __shared__ __align__(16) short H1[2][1024];
    __shared__ __align__(16) float PS[2][16][20];

    for (int i = tid; i < 1024; i += NTH){
        H0[0][i]=0; H0[1][i]=0; H1[0][i]=0; H1[1][i]=0;
    }
    if (tid < 2*16*20) (&PS[0][0][0])[tid] = 0.f;

    // ---- persistent weight fragments & epilogue constants (one tile per wave) ----
    bf16x8 Ahi0[2], Alo0[2], Ahi1[4], Alo1[4];
    f32x4 bias0v, bias1v, wih0v;
    float wlinv = 0.f;
    int   widx4 = 0;

    {
        const int ar = 16*m + n;              // A-row = gate g = 4j + r
        const int aj = ar >> 2, arr = ar & 3;
        const bool rowv = cw && (aj < HID);
        const int orow = arr*HID + aj;
        const float gsc = (arr == 2) ? 2.f*LOG2E : LOG2E;   // pre-scale into exp2 domain
        #pragma unroll
        for (int kb=0; kb<2; ++kb){
            bf16x8 hi, lo;
            #pragma unroll
            for (int jj=0; jj<8; ++jj){
                const int k = kb*32 + 8*p + jj;
                const float wv = (rowv && k < HID) ? gsc * W_hh0[orow*HID + k] : 0.f;
                const unsigned short hb = f2bf(wv);
                hi[jj] = (short)hb;
                lo[jj] = (short)f2bf(wv - bf2f(hb));
            }
            Ahi0[kb] = hi; Alo0[kb] = lo;
        }
        #pragma unroll
        for (int kb=0; kb<4; ++kb){
            bf16x8 hi, lo;
            #pragma unroll
            for (int jj=0; jj<8; ++jj){
                const int k = kb*32 + 8*p + jj;   // 0..127: [h0 (64) ; h1 (64)]
                float wv = 0.f;
                if (rowv){
                    if (k < 64) { if (k < HID) wv = W_ih1[orow*HID + k]; }
                    else        { const int kk = k - 64; if (kk < HID) wv = W_hh1[orow*HID + kk]; }
                }
                wv *= gsc;
                const unsigned short hb = f2bf(wv);
                hi[jj] = (short)hb;
                lo[jj] = (short)f2bf(wv - bf2f(hb));
            }
            Ahi1[kb] = hi; Alo1[kb] = lo;
        }
        const int je = 4*m + p;               // unit this lane owns in epilogue
        const bool jev = cw && (je < HID);
        const bool bmask = jev && (n < NBATCH);   // bias/x/proj only in real cols
        #pragma unroll
        for (int r4=0; r4<4; ++r4){
            const float gs4 = (r4 == 2) ? 2.f*LOG2E : LOG2E;
            const int oe = r4*HID + je;
            bias0v[r4] = bmask ? gs4 * (b_ih0[oe] + b_hh0[oe]) : 0.f;
            bias1v[r4] = bmask ? gs4 * (b_ih1[oe] + b_hh1[oe]) : 0.f;
            wih0v[r4] = bmask ? gs4 * W_ih0[oe] : 0.f;
        }
        wlinv = bmask ? W_lin[je] : 0.f;
        widx4 = ((je>>5)<<9) + (n + ((je>>3)&3)*16)*8 + (je&7);
    }

    const long long bb = (long long)blockIdx.x * NBATCH;
    const float* xr = x + (bb + (n < NBATCH ? n : NBATCH-1)) * TLEN;
    float xv = xr[0];
    float c0a = 0.f, c1a = 0.f;
    const float blin = b_lin[0];
    const bool lo_lane = (n >= 4 && n < 8);
    const bool hi8_lane = (n >= 8);

    __syncthreads();

    // Pipelined loop: iter s = layer0(s) || layer1(s-1) || out(s-2). ONE barrier.
    // Stagger: even waves L0 then L1; odd waves L1 then L0.
    for (int s = 0; s <= TLEN; ++s){
        const int pw = s & 1, pr = pw ^ 1;
        const float xnx = xr[(s+1 < TLEN) ? s+1 : TLEN-1];

        // B-fragments: h0(s-1) (both layers) and h1(s-2) — packed arrays
        bf16x8 rb[2], r1[2];
        if (cw){
            #pragma unroll
            for (int kb=0; kb<2; ++kb){
                rb[kb] = *reinterpret_cast<const bf16x8*>(&H0[pr][kb*512 + l*8]);
                r1[kb] = *reinterpret_cast<const bf16x8*>(&H1[pw][kb*512 + l*8]);
            }
        }

        // out(s-2): wave 13 sums PS written at iter s-1
        if (s >= 2 && w == 13 && l < NBATCH){
            const float4 p0 = *reinterpret_cast<const float4*>(&PS[pr][l][0]);
            const float4 p1 = *reinterpret_cast<const float4*>(&PS[pr][l][4]);
            const float4 p2 = *reinterpret_cast<const float4*>(&PS[pr][l][8]);
            const float4 p3 = *reinterpret_cast<const float4*>(&PS[pr][l][12]);
            const float s01 = (p0.x + p0.y) + (p0.z + p0.w);
            const float s23 = (p1.x + p1.y) + (p1.z + p1.w);
            const float s45 = (p2.x + p2.y) + (p2.z + p2.w);
            const float s67 = (p3.x + p3.y) + (p3.z + p3.w);
            out[(bb + l)*TLEN + (s-2)] = ((s01 + s23) + (s45 + s67)) + blin;
        }

        // ---------------- layer 0, step s ----------------
        auto doL0 = [&](){
            if (cw && s < TLEN){
                f32x4 C1 = bias0v;
                #pragma unroll
                for (int r4=0; r4<4; ++r4) C1[r4] = fmaf(xv, wih0v[r4], C1[r4]);
                f32x4 C2 = {0.f,0.f,0.f,0.f};
                __builtin_amdgcn_s_setprio(1);
                C1 = __builtin_amdgcn_mfma_f32_16x16x32_bf16(Ahi0[0], rb[0], C1, 0,0,0);
                C1 = __builtin_amdgcn_mfma_f32_16x16x32_bf16(Ahi0[1], rb[1], C1, 0,0,0);
                C2 = __builtin_amdgcn_mfma_f32_16x16x32_bf16(Alo0[0], rb[0], C2, 0,0,0);
                C2 = __builtin_amdgcn_mfma_f32_16x16x32_bf16(Alo0[1], rb[1], C2, 0,0,0);
                __builtin_amdgcn_s_setprio(0);
                f32x4 pre;
                #pragma unroll
                for (int r4=0; r4<4; ++r4){
                    const float t = C1[r4] + __shfl_xor(C1[r4], 4, 64);
                    const float u = __shfl_xor(C2[r4], 8, 64);
                    pre[r4] = t + u;
                }
                const float gi = sigm2(pre[0]);
                const float gf = sigm2(pre[1]);
                const float gg = fmaf(2.f, sigm2(pre[2]), -1.f);
                const float go = sigm2(pre[3]);
                c0a = fmaf(gf, c0a, gi*gg);
                const float hv = go * tanh_c(c0a);
                const float hv8 = __shfl_xor(hv, 8, 64);
                const float hsel = hi8_lane ? hv8 : hv;
                const unsigned u0 = cvt1bf(hsel);
                const unsigned u1 = cvt1bf(hsel - bf2f((unsigned short)u0));
                H0[pw][widx4] = (short)(lo_lane ? u1 : u0);
            }
        };

        // ---------------- layer 1, step s-1 + projection ----------------
        auto doL1 = [&](){
            if (cw && s >= 1){
                f32x4 C1 = bias1v;
                f32x4 C2 = {0.f,0.f,0.f,0.f};
                __builtin_amdgcn_s_setprio(1);
                C1 = __builtin_amdgcn_mfma_f32_16x16x32_bf16(Ahi1[0], rb[0], C1, 0,0,0);
                C1 = __builtin_amdgcn_mfma_f32_16x16x32_bf16(Ahi1[1], rb[1], C1, 0,0,0);
                C1 = __builtin_amdgcn_mfma_f32_16x16x32_bf16(Ahi1[2], r1[0], C1, 0,0,0);
                C1 = __builtin_amdgcn_mfma_f32_16x16x32_bf16(Ahi1[3], r1[1], C1, 0,0,0);
                C2 = __builtin_amdgcn_mfma_f32_16x16x32_bf16(Alo1[0], rb[0], C2, 0,0,0);
                C2 = __builtin_amdgcn_mfma_f32_16x16x32_bf16(Alo1[1], rb[1], C2, 0,0,0);
                C2 = __builtin_amdgcn_mfma_f32_16x16x32_bf16(Alo1[2], r1[0], C2, 0,0,0);
                C2 = __builtin_amdgcn_mfma_f32_16x16x32_bf16(Alo1[3], r1[1], C2, 0,0,0);
                __builtin_amdgcn_s_setprio(0);
                f32x4 pre;
                #pragma unroll
                for (int r4=0; r4<4; ++r4){
                    const float t = C1[r4] + __shfl_xor(C1[r4], 4, 64);
                    const float u = __shfl_xor(C2[r4], 8, 64);
                    pre[r4] = t + u;
                }
                const float gi = sigm2(pre[0]);
                const float gf = sigm2(pre[1]);
                const float gg = fmaf(2.f, sigm2(pre[2]), -1.f);
                const float go = sigm2(pre[3]);
                c1a = fmaf(gf, c1a, gi*gg);
                const float hv = go * tanh_c(c1a);
                const float hv8 = __shfl_xor(hv, 8, 64);
                const float hsel = hi8_lane ? hv8 : hv;
                const unsigned u0 = cvt1bf(hsel);
                const unsigned u1 = cvt1bf(hsel - bf2f((unsigned short)u0));
                H1[pr][widx4] = (short)(lo_lane ? u1 : u0);
                float ph = hv * wlinv;                 // masked to cols 0-3
                ph += __shfl_xor(ph, 16, 64);
                ph += __shfl_xor(ph, 32, 64);
                if (l < 16) PS[pw][l][w] = ph;
            }
        };

        if (w & 1){ doL1(); doL0(); } else { doL0(); doL1(); }

        __syncthreads();
        xv = xnx;
    }

    // tail: out(1023) from PS written at s=1024 (parity 0)
    if (w == 13 && l < NBATCH){
        const float4 p0 = *reinterpret_cast<const float4*>(&PS[0][l][0]);
        const float4 p1 = *reinterpret_cast<const float4*>(&PS[0][l][4]);
        const float4 p2 = *reinterpret_cast<const float4*>(&PS[0][l][8]);
        const float4 p3 = *reinterpret_cast<const float4*>(&PS[0][l][12]);
        const float s01 = (p0.x + p0.y) + (p0.z + p0.w);
        const float s23 = (p1.x + p1.y) + (p1.z + p1.w);
        const float s45 = (p2.x + p2.y) + (p2.z + p2.w);
        const float s67 = (p3.x + p3.y) + (p3.z + p3.w);
        out[(bb + l)*TLEN + (TLEN-1)] = ((s01 + s23) + (s45 + s67)) + blin;
    }
}

extern "C" void kernel_launch(void* const* d_in, const int* in_sizes, int n_in,
                              void* d_out, int out_size, void* d_ws, size_t ws_size,
                              hipStream_t stream) {
    const float* x     = (const float*)d_in[0];
    const float* W_ih0 = (const float*)d_in[1];
    const float* W_hh0 = (const float*)d_in[2];
    const float* b_ih0 = (const float*)d_in[3];
    const float* b_hh0 = (const float*)d_in[4];
    const float* W_ih1 = (const float*)d_in[5];
    const float* W_hh1 = (const float*)d_in[6];
    const float* b_ih1 = (const float*)d_in[7];
    const float* b_hh1 = (const float*)d_in[8];
    const float* W_lin = (const float*)d_in[9];
    const float* b_lin = (const float*)d_in[10];
    float* out = (float*)d_out;

    const int B = in_sizes[0] / TLEN;
    lstm2_mfma<<<dim3(B / NBATCH), dim3(NTH), 0, stream>>>(
        x, W_ih0, W_hh0, b_ih0, b_hh0, W_ih1, W_hh1, b_ih1, b_hh1, W_lin, b_lin, out);
}

// Round 12
// 1114.937 us; speedup vs baseline: 1.2103x; 1.2103x over previous
//
#include <hip/hip_runtime.h>

#define HID 51
#define TLEN 1024
#define NBATCH 4
#define NW 14             // 13 compute waves + 1 out wave
#define NTH (NW * 64)

typedef _Float16 f16x8 __attribute__((ext_vector_type(8)));
typedef float    f32x4 __attribute__((ext_vector_type(4)));

#define LOG2E 1.4426950408889634f

__device__ __forceinline__ float frcp(float v){ return __builtin_amdgcn_rcpf(v); }
// input already scaled by log2e (or 2*log2e for tanh-gate)
__device__ __forceinline__ float sigm2(float v){ return frcp(1.f + __builtin_amdgcn_exp2f(-v)); }
__device__ __forceinline__ float tanh_c(float c){   // c in true domain
    return fmaf(2.f, frcp(1.f + __builtin_amdgcn_exp2f(-2.f*LOG2E*c)), -1.f);
}

// LDS h layout = MFMA B-fragment-linear (validated R4): lane l reads 16B at
// half-index kb*512 + l*8 covering k = 32*kb + 8*(l>>4) + 0..7, col = l&15.
// Writer (unit j, col n): half-index = (j>>5)*512 + (n + ((j>>3)&3)*16)*8 + (j&7).
// Cols 0-3 = real batch; cols 4-15 duplicate batch 3 (uniform, harmless — R9 scheme).
// Precision: W = fp16_hi + fp16_lo (systematic error ~2^-21), h = single fp16
// (random per-step error 2^-11, gate-damped). pre = (Whi+Wlo)·h, two acc chains.

__global__ __launch_bounds__(NTH)
void lstm2_mfma(const float* __restrict__ x,
                const float* __restrict__ W_ih0, const float* __restrict__ W_hh0,
                const float* __restrict__ b_ih0, const float* __restrict__ b_hh0,
                const float* __restrict__ W_ih1, const float* __restrict__ W_hh1,
                const float* __restrict__ b_ih1, const float* __restrict__ b_hh1,
                const float* __restrict__ W_lin, const float* __restrict__ b_lin,
                float* __restrict__ out)
{
    const int tid = threadIdx.x;
    const int w = tid >> 6;          // wave 0..13; waves 0..12 compute tile m=w
    const int l = tid & 63;          // lane
    const int n = l & 15;            // column slot (batch col, 4-15 dup batch 3)
    const int p = l >> 4;            // lane group 0..3
    const int m = w;                 // M-tile id
    const bool cw = (m < 13);        // compute wave?

    __shared__ _Float16 H0[2][1024];
    __shared__ _Float16 H1[2][1024];
    __shared__ __align__(16) float PS[2][16][20];

    for (int i = tid; i < 1024; i += NTH){
        H0[0][i] = (_Float16)0.f; H0[1][i] = (_Float16)0.f;
        H1[0][i] = (_Float16)0.f; H1[1][i] = (_Float16)0.f;
    }
    if (tid < 2*16*20) (&PS[0][0][0])[tid] = 0.f;

    // ---- persistent weight fragments (fp16 hi/lo) & epilogue constants ----
    f16x8 A0h[2], A0l[2];            // W_hh0 hi/lo, K=64
    f16x8 A1h[4], A1l[4];            // [0..1]=W_ih1 (k0-63), [2..3]=W_hh1 (k64-127)
    f32x4 bias0v, bias1v, wih0v;
    float wlinv = 0.f;
    int   widx4 = 0;

    {
        const int ar = 16*m + n;              // A-row = gate g = 4j + r
        const int aj = ar >> 2, arr = ar & 3;
        const bool rowv = cw && (aj < HID);
        const int orow = arr*HID + aj;
        const float gsc = (arr == 2) ? 2.f*LOG2E : LOG2E;   // pre-scale into exp2 domain
        #pragma unroll
        for (int kb=0; kb<2; ++kb){
            f16x8 hi, lo;
            #pragma unroll
            for (int jj=0; jj<8; ++jj){
                const int k = kb*32 + 8*p + jj;
                const float wv = (rowv && k < HID) ? gsc * W_hh0[orow*HID + k] : 0.f;
                const _Float16 h = (_Float16)wv;
                hi[jj] = h;
                lo[jj] = (_Float16)(wv - (float)h);
            }
            A0h[kb] = hi; A0l[kb] = lo;
        }
        #pragma unroll
        for (int kb=0; kb<4; ++kb){
            f16x8 hi, lo;
            #pragma unroll
            for (int jj=0; jj<8; ++jj){
                const int k = kb*32 + 8*p + jj;   // 0..127: [h0 (64) ; h1 (64)]
                float wv = 0.f;
                if (rowv){
                    if (k < 64) { if (k < HID) wv = W_ih1[orow*HID + k]; }
                    else        { const int kk = k - 64; if (kk < HID) wv = W_hh1[orow*HID + kk]; }
                }
                wv *= gsc;
                const _Float16 h = (_Float16)wv;
                hi[jj] = h;
                lo[jj] = (_Float16)(wv - (float)h);
            }
            A1h[kb] = hi; A1l[kb] = lo;
        }
        const int je = 4*m + p;               // unit this lane owns in epilogue
        const bool jev = cw && (je < HID);
        #pragma unroll
        for (int r4=0; r4<4; ++r4){
            const float gs4 = (r4 == 2) ? 2.f*LOG2E : LOG2E;
            const int oe = r4*HID + je;
            bias0v[r4] = jev ? gs4 * (b_ih0[oe] + b_hh0[oe]) : 0.f;
            bias1v[r4] = jev ? gs4 * (b_ih1[oe] + b_hh1[oe]) : 0.f;
            wih0v[r4] = jev ? gs4 * W_ih0[oe] : 0.f;
        }
        wlinv = jev ? W_lin[je] : 0.f;
        widx4 = ((je>>5)<<9) + (n + ((je>>3)&3)*16)*8 + (je&7);
    }

    const long long bb = (long long)blockIdx.x * NBATCH;
    const float* xr = x + (bb + (n < NBATCH ? n : NBATCH-1)) * TLEN;
    float xv = xr[0];
    float c0a = 0.f, c1a = 0.f;
    const float blin = b_lin[0];

    __syncthreads();

    // Pipelined loop: iter s = layer0(s) || layer1(s-1) || out(s-2). ONE barrier.
    // Stagger: even waves L0 then L1; odd waves L1 then L0.
    for (int s = 0; s <= TLEN; ++s){
        const int pw = s & 1, pr = pw ^ 1;
        const float xnx = xr[(s+1 < TLEN) ? s+1 : TLEN-1];

        // B-fragments: h0(s-1) (both layers) and h1(s-2)
        f16x8 rb[2], r1[2];
        if (cw){
            #pragma unroll
            for (int kb=0; kb<2; ++kb){
                rb[kb] = *reinterpret_cast<const f16x8*>(&H0[pr][kb*512 + l*8]);
                r1[kb] = *reinterpret_cast<const f16x8*>(&H1[pw][kb*512 + l*8]);
            }
        }

        // out(s-2): wave 13 sums PS written at iter s-1 (cols 13-19 stay 0)
        if (s >= 2 && w == 13 && l < NBATCH){
            const float4 p0 = *reinterpret_cast<const float4*>(&PS[pr][l][0]);
            const float4 p1 = *reinterpret_cast<const float4*>(&PS[pr][l][4]);
            const float4 p2 = *reinterpret_cast<const float4*>(&PS[pr][l][8]);
            const float4 p3 = *reinterpret_cast<const float4*>(&PS[pr][l][12]);
            const float s01 = (p0.x + p0.y) + (p0.z + p0.w);
            const float s23 = (p1.x + p1.y) + (p1.z + p1.w);
            const float s45 = (p2.x + p2.y) + (p2.z + p2.w);
            const float s67 = (p3.x + p3.y) + (p3.z + p3.w);
            out[(bb + l)*TLEN + (s-2)] = ((s01 + s23) + (s45 + s67)) + blin;
        }

        // ---------------- layer 0, step s ----------------
        auto doL0 = [&](){
            if (cw && s < TLEN){
                f32x4 a0 = bias0v;
                #pragma unroll
                for (int r4=0; r4<4; ++r4) a0[r4] = fmaf(xv, wih0v[r4], a0[r4]);
                f32x4 a1 = {0.f,0.f,0.f,0.f};
                __builtin_amdgcn_s_setprio(1);
                a0 = __builtin_amdgcn_mfma_f32_16x16x32_f16(A0h[0], rb[0], a0, 0,0,0);
                a0 = __builtin_amdgcn_mfma_f32_16x16x32_f16(A0h[1], rb[1], a0, 0,0,0);
                a1 = __builtin_amdgcn_mfma_f32_16x16x32_f16(A0l[0], rb[0], a1, 0,0,0);
                a1 = __builtin_amdgcn_mfma_f32_16x16x32_f16(A0l[1], rb[1], a1, 0,0,0);
                __builtin_amdgcn_s_setprio(0);
                const f32x4 pre = a0 + a1;
                const float gi = sigm2(pre[0]);
                const float gf = sigm2(pre[1]);
                const float gg = fmaf(2.f, sigm2(pre[2]), -1.f);
                const float go = sigm2(pre[3]);
                c0a = fmaf(gf, c0a, gi*gg);
                const float hv = go * tanh_c(c0a);
                H0[pw][widx4] = (_Float16)hv;
            }
        };

        // ---------------- layer 1, step s-1 + projection ----------------
        auto doL1 = [&](){
            if (cw && s >= 1){
                f32x4 b0 = bias1v;
                f32x4 b1 = {0.f,0.f,0.f,0.f};
                __builtin_amdgcn_s_setprio(1);
                b0 = __builtin_amdgcn_mfma_f32_16x16x32_f16(A1h[0], rb[0], b0, 0,0,0);
                b0 = __builtin_amdgcn_mfma_f32_16x16x32_f16(A1h[1], rb[1], b0, 0,0,0);
                b1 = __builtin_amdgcn_mfma_f32_16x16x32_f16(A1l[0], rb[0], b1, 0,0,0);
                b1 = __builtin_amdgcn_mfma_f32_16x16x32_f16(A1l[1], rb[1], b1, 0,0,0);
                b0 = __builtin_amdgcn_mfma_f32_16x16x32_f16(A1h[2], r1[0], b0, 0,0,0);
                b0 = __builtin_amdgcn_mfma_f32_16x16x32_f16(A1h[3], r1[1], b0, 0,0,0);
                b1 = __builtin_amdgcn_mfma_f32_16x16x32_f16(A1l[2], r1[0], b1, 0,0,0);
                b1 = __builtin_amdgcn_mfma_f32_16x16x32_f16(A1l[3], r1[1], b1, 0,0,0);
                __builtin_amdgcn_s_setprio(0);
                const f32x4 pre = b0 + b1;
                const float gi = sigm2(pre[0]);
                const float gf = sigm2(pre[1]);
                const float gg = fmaf(2.f, sigm2(pre[2]), -1.f);
                const float go = sigm2(pre[3]);
                c1a = fmaf(gf, c1a, gi*gg);
                const float hv = go * tanh_c(c1a);
                H1[pr][widx4] = (_Float16)hv;
                float ph = hv * wlinv;
                ph += __shfl_xor(ph, 16, 64);
                ph += __shfl_xor(ph, 32, 64);
                if (l < 16) PS[pw][l][w] = ph;
            }
        };

        if (w & 1){ doL1(); doL0(); } else { doL0(); doL1(); }

        __syncthreads();
        xv = xnx;
    }

    // tail: out(1023) from PS written at s=1024 (parity 0)
    if (w == 13 && l < NBATCH){
        const float4 p0 = *reinterpret_cast<const float4*>(&PS[0][l][0]);
        const float4 p1 = *reinterpret_cast<const float4*>(&PS[0][l][4]);
        const float4 p2 = *reinterpret_cast<const float4*>(&PS[0][l][8]);
        const float4 p3 = *reinterpret_cast<const float4*>(&PS[0][l][12]);
        const float s01 = (p0.x + p0.y) + (p0.z + p0.w);
        const float s23 = (p1.x + p1.y) + (p1.z + p1.w);
        const float s45 = (p2.x + p2.y) + (p2.z + p2.w);
        const float s67 = (p3.x + p3.y) + (p3.z + p3.w);
        out[(bb + l)*TLEN + (TLEN-1)] = ((s01 + s23) + (s45 + s67)) + blin;
    }
}

extern "C" void kernel_launch(void* const* d_in, const int* in_sizes, int n_in,
                              void* d_out, int out_size, void* d_ws, size_t ws_size,
                              hipStream_t stream) {
    const float* x     = (const float*)d_in[0];
    const float* W_ih0 = (const float*)d_in[1];
    const float* W_hh0 = (const float*)d_in[2];
    const float* b_ih0 = (const float*)d_in[3];
    const float* b_hh0 = (const float*)d_in[4];
    const float* W_ih1 = (const float*)d_in[5];
    const float* W_hh1 = (const float*)d_in[6];
    const float* b_ih1 = (const float*)d_in[7];
    const float* b_hh1 = (const float*)d_in[8];
    const float* W_lin = (const float*)d_in[9];
    const float* b_lin = (const float*)d_in[10];
    float* out = (float*)d_out;

    const int B = in_sizes[0] / TLEN;
    lstm2_mfma<<<dim3(B / NBATCH), dim3(NTH), 0, stream>>>(
        x, W_ih0, W_hh0, b_ih0, b_hh0, W_ih1, W_hh1, b_ih1, b_hh1, W_lin, b_lin, out);
}

// Round 13
// 942.703 us; speedup vs baseline: 1.4314x; 1.1827x over previous
//
#include <hip/hip_runtime.h>

#define HID 51
#define TLEN 1024
#define NBATCH 4
#define NW 14             // 13 compute waves + 1 out wave
#define NTH (NW * 64)

typedef _Float16 f16x8 __attribute__((ext_vector_type(8)));
typedef float    f32x4 __attribute__((ext_vector_type(4)));

#define LOG2E 1.4426950408889634f

__device__ __forceinline__ float frcp(float v){ return __builtin_amdgcn_rcpf(v); }
// input already scaled by log2e (or 2*log2e for tanh-gate)
__device__ __forceinline__ float sigm2(float v){ return frcp(1.f + __builtin_amdgcn_exp2f(-v)); }
__device__ __forceinline__ float tanh_c(float c){   // c in true domain
    return fmaf(2.f, frcp(1.f + __builtin_amdgcn_exp2f(-2.f*LOG2E*c)), -1.f);
}

// LDS h layout = MFMA B-fragment-linear (validated R4): lane l reads 16B at
// half-index kb*512 + l*8 covering k = 32*kb + 8*(l>>4) + 0..7, col = l&15.
// Writer (unit j, col n): half-index = (j>>5)*512 + (n + ((j>>3)&3)*16)*8 + (j&7).
// Cols 0-3 = real batch; cols 4-15 stay ZERO (writes masked to n<4) -> C cols
// 4-15 are exactly 0, never read.
// Precision: single fp16 weights (systematic ~2^-12) + fp16 h (random 2^-11),
// f32 MFMA accumulate + f32 cell state. Spends the measured margin vs threshold.

__global__ __launch_bounds__(NTH)
void lstm2_mfma(const float* __restrict__ x,
                const float* __restrict__ W_ih0, const float* __restrict__ W_hh0,
                const float* __restrict__ b_ih0, const float* __restrict__ b_hh0,
                const float* __restrict__ W_ih1, const float* __restrict__ W_hh1,
                const float* __restrict__ b_ih1, const float* __restrict__ b_hh1,
                const float* __restrict__ W_lin, const float* __restrict__ b_lin,
                float* __restrict__ out)
{
    const int tid = threadIdx.x;
    const int w = tid >> 6;          // wave 0..13; waves 0..12 compute tile m=w
    const int l = tid & 63;          // lane
    const int n = l & 15;            // column slot (0-3 real batch)
    const int p = l >> 4;            // lane group 0..3
    const int m = w;                 // M-tile id
    const bool cw = (m < 13);        // compute wave?

    __shared__ _Float16 H0[2][1024];
    __shared__ _Float16 H1[2][1024];
    __shared__ __align__(16) float PS[2][16][20];

    for (int i = tid; i < 1024; i += NTH){
        H0[0][i] = (_Float16)0.f; H0[1][i] = (_Float16)0.f;
        H1[0][i] = (_Float16)0.f; H1[1][i] = (_Float16)0.f;
    }
    if (tid < 2*16*20) (&PS[0][0][0])[tid] = 0.f;

    // ---- persistent weight fragments (single fp16) & epilogue constants ----
    f16x8 A0[2];                      // W_hh0, K=64
    f16x8 A1[4];                      // [0..1]=W_ih1 (k0-63), [2..3]=W_hh1 (k64-127)
    f32x4 bias0v, bias1v, wih0v;
    float wlinv = 0.f;
    int   widx4 = 0;

    {
        const int ar = 16*m + n;              // A-row = gate g = 4j + r
        const int aj = ar >> 2, arr = ar & 3;
        const bool rowv = cw && (aj < HID);
        const int orow = arr*HID + aj;
        const float gsc = (arr == 2) ? 2.f*LOG2E : LOG2E;   // pre-scale into exp2 domain
        #pragma unroll
        for (int kb=0; kb<2; ++kb){
            f16x8 hi;
            #pragma unroll
            for (int jj=0; jj<8; ++jj){
                const int k = kb*32 + 8*p + jj;
                const float wv = (rowv && k < HID) ? gsc * W_hh0[orow*HID + k] : 0.f;
                hi[jj] = (_Float16)wv;
            }
            A0[kb] = hi;
        }
        #pragma unroll
        for (int kb=0; kb<4; ++kb){
            f16x8 hi;
            #pragma unroll
            for (int jj=0; jj<8; ++jj){
                const int k = kb*32 + 8*p + jj;   // 0..127: [h0 (64) ; h1 (64)]
                float wv = 0.f;
                if (rowv){
                    if (k < 64) { if (k < HID) wv = W_ih1[orow*HID + k]; }
                    else        { const int kk = k - 64; if (kk < HID) wv = W_hh1[orow*HID + kk]; }
                }
                hi[jj] = (_Float16)(wv * gsc);
            }
            A1[kb] = hi;
        }
        const int je = 4*m + p;               // unit this lane owns in epilogue
        const bool jev = cw && (je < HID);
        #pragma unroll
        for (int r4=0; r4<4; ++r4){
            const float gs4 = (r4 == 2) ? 2.f*LOG2E : LOG2E;
            const int oe = r4*HID + je;
            bias0v[r4] = jev ? gs4 * (b_ih0[oe] + b_hh0[oe]) : 0.f;
            bias1v[r4] = jev ? gs4 * (b_ih1[oe] + b_hh1[oe]) : 0.f;
            wih0v[r4] = jev ? gs4 * W_ih0[oe] : 0.f;
        }
        wlinv = jev ? W_lin[je] : 0.f;
        widx4 = ((je>>5)<<9) + (n + ((je>>3)&3)*16)*8 + (je&7);
    }

    const long long bb = (long long)blockIdx.x * NBATCH;
    const float* xr = x + (bb + (n < NBATCH ? n : NBATCH-1)) * TLEN;
    float xv = xr[0];
    float c0a = 0.f, c1a = 0.f;
    const float blin = b_lin[0];
    const bool wmask = (n < NBATCH);   // only real-batch columns write h

    __syncthreads();

    // Pipelined loop: iter s = layer0(s) || layer1(s-1) || out(s-2). ONE barrier.
    // Stagger: even waves L0 then L1; odd waves L1 then L0.
    for (int s = 0; s <= TLEN; ++s){
        const int pw = s & 1, pr = pw ^ 1;
        const float xnx = xr[(s+1 < TLEN) ? s+1 : TLEN-1];

        // B-fragments: h0(s-1) (both layers) and h1(s-2)
        f16x8 rb[2], r1[2];
        if (cw){
            #pragma unroll
            for (int kb=0; kb<2; ++kb){
                rb[kb] = *reinterpret_cast<const f16x8*>(&H0[pr][kb*512 + l*8]);
                r1[kb] = *reinterpret_cast<const f16x8*>(&H1[pw][kb*512 + l*8]);
            }
        }

        // out(s-2): wave 13 sums PS written at iter s-1 (cols 13-19 stay 0)
        if (s >= 2 && w == 13 && l < NBATCH){
            const float4 p0 = *reinterpret_cast<const float4*>(&PS[pr][l][0]);
            const float4 p1 = *reinterpret_cast<const float4*>(&PS[pr][l][4]);
            const float4 p2 = *reinterpret_cast<const float4*>(&PS[pr][l][8]);
            const float4 p3 = *reinterpret_cast<const float4*>(&PS[pr][l][12]);
            const float s01 = (p0.x + p0.y) + (p0.z + p0.w);
            const float s23 = (p1.x + p1.y) + (p1.z + p1.w);
            const float s45 = (p2.x + p2.y) + (p2.z + p2.w);
            const float s67 = (p3.x + p3.y) + (p3.z + p3.w);
            out[(bb + l)*TLEN + (s-2)] = ((s01 + s23) + (s45 + s67)) + blin;
        }

        // ---------------- layer 0, step s ----------------
        auto doL0 = [&](){
            if (cw && s < TLEN){
                f32x4 a0 = bias0v;
                #pragma unroll
                for (int r4=0; r4<4; ++r4) a0[r4] = fmaf(xv, wih0v[r4], a0[r4]);
                __builtin_amdgcn_s_setprio(1);
                a0 = __builtin_amdgcn_mfma_f32_16x16x32_f16(A0[0], rb[0], a0, 0,0,0);
                a0 = __builtin_amdgcn_mfma_f32_16x16x32_f16(A0[1], rb[1], a0, 0,0,0);
                __builtin_amdgcn_s_setprio(0);
                const float gi = sigm2(a0[0]);
                const float gf = sigm2(a0[1]);
                const float gg = fmaf(2.f, sigm2(a0[2]), -1.f);
                const float go = sigm2(a0[3]);
                c0a = fmaf(gf, c0a, gi*gg);
                const float hv = go * tanh_c(c0a);
                if (wmask) H0[pw][widx4] = (_Float16)hv;
            }
        };

        // ---------------- layer 1, step s-1 + projection ----------------
        auto doL1 = [&](){
            if (cw && s >= 1){
                f32x4 b0 = bias1v;
                f32x4 b1 = {0.f,0.f,0.f,0.f};
                __builtin_amdgcn_s_setprio(1);
                b0 = __builtin_amdgcn_mfma_f32_16x16x32_f16(A1[0], rb[0], b0, 0,0,0);
                b0 = __builtin_amdgcn_mfma_f32_16x16x32_f16(A1[1], rb[1], b0, 0,0,0);
                b1 = __builtin_amdgcn_mfma_f32_16x16x32_f16(A1[2], r1[0], b1, 0,0,0);
                b1 = __builtin_amdgcn_mfma_f32_16x16x32_f16(A1[3], r1[1], b1, 0,0,0);
                __builtin_amdgcn_s_setprio(0);
                const f32x4 pre = b0 + b1;
                const float gi = sigm2(pre[0]);
                const float gf = sigm2(pre[1]);
                const float gg = fmaf(2.f, sigm2(pre[2]), -1.f);
                const float go = sigm2(pre[3]);
                c1a = fmaf(gf, c1a, gi*gg);
                const float hv = go * tanh_c(c1a);
                if (wmask) H1[pr][widx4] = (_Float16)hv;
                float ph = hv * wlinv;
                ph += __shfl_xor(ph, 16, 64);
                ph += __shfl_xor(ph, 32, 64);
                if (l < 16) PS[pw][l][w] = ph;
            }
        };

        if (w & 1){ doL1(); doL0(); } else { doL0(); doL1(); }

        __syncthreads();
        xv = xnx;
    }

    // tail: out(1023) from PS written at s=1024 (parity 0)
    if (w == 13 && l < NBATCH){
        const float4 p0 = *reinterpret_cast<const float4*>(&PS[0][l][0]);
        const float4 p1 = *reinterpret_cast<const float4*>(&PS[0][l][4]);
        const float4 p2 = *reinterpret_cast<const float4*>(&PS[0][l][8]);
        const float4 p3 = *reinterpret_cast<const float4*>(&PS[0][l][12]);
        const float s01 = (p0.x + p0.y) + (p0.z + p0.w);
        const float s23 = (p1.x + p1.y) + (p1.z + p1.w);
        const float s45 = (p2.x + p2.y) + (p2.z + p2.w);
        const float s67 = (p3.x + p3.y) + (p3.z + p3.w);
        out[(bb + l)*TLEN + (TLEN-1)] = ((s01 + s23) + (s45 + s67)) + blin;
    }
}

extern "C" void kernel_launch(void* const* d_in, const int* in_sizes, int n_in,
                              void* d_out, int out_size, void* d_ws, size_t ws_size,
                              hipStream_t stream) {
    const float* x     = (const float*)d_in[0];
    const float* W_ih0 = (const float*)d_in[1];
    const float* W_hh0 = (const float*)d_in[2];
    const float* b_ih0 = (const float*)d_in[3];
    const float* b_hh0 = (const float*)d_in[4];
    const float* W_ih1 = (const float*)d_in[5];
    const float* W_hh1 = (const float*)d_in[6];
    const float* b_ih1 = (const float*)d_in[7];
    const float* b_hh1 = (const float*)d_in[8];
    const float* W_lin = (const float*)d_in[9];
    const float* b_lin = (const float*)d_in[10];
    float* out = (float*)d_out;

    const int B = in_sizes[0] / TLEN;
    lstm2_mfma<<<dim3(B / NBATCH), dim3(NTH), 0, stream>>>(
        x, W_ih0, W_hh0, b_ih0, b_hh0, W_ih1, W_hh1, b_ih1, b_hh1, W_lin, b_lin, out);
}

// Round 14
// 732.859 us; speedup vs baseline: 1.8412x; 1.2863x over previous
//
#include <hip/hip_runtime.h>

#define HID 51
#define TLEN 1024
#define NBATCH 4
#define NW 13
#define NTH (NW * 64)    // 832 threads

typedef _Float16 f16x8 __attribute__((ext_vector_type(8)));
typedef float    f32x4 __attribute__((ext_vector_type(4)));

#define LOG2E 1.4426950408889634f

__device__ __forceinline__ float frcp(float v){ return __builtin_amdgcn_rcpf(v); }
// input already scaled by log2e (or 2*log2e for tanh-gate)
__device__ __forceinline__ float sigm2(float v){ return frcp(1.f + __builtin_amdgcn_exp2f(-v)); }
__device__ __forceinline__ float tanh_c(float c){   // c in true domain
    return fmaf(2.f, frcp(1.f + __builtin_amdgcn_exp2f(-2.f*LOG2E*c)), -1.f);
}

// Fragment layout (validated R4): lane l reads 16B at half-index kb*512 + l*8
// covering k = 32*kb + 8*(l>>4) + 0..7, col = l&15.
// Writer (unit j, col n): half-index = (j>>5)<<9 + (n + ((j>>3)&3)*16)*8 + (j&7).
// Phase A: 13 GEMM waves -> raw gate pre-activations to PRE[layer*204 + j*4 + n].
// Phase B: one epilogue chain per lane (q = tid < 408), h -> fragment LDS.
// Projection: M-row 204 of tile 12 carries W_lin over the h1 K-range -> pre1[0]
// of lane (p==3, n) = dot(W_lin, h1(s-2)); out written in phase A (lag 2).

__global__ __launch_bounds__(NTH)
void lstm2_mfma(const float* __restrict__ x,
                const float* __restrict__ W_ih0, const float* __restrict__ W_hh0,
                const float* __restrict__ b_ih0, const float* __restrict__ b_hh0,
                const float* __restrict__ W_ih1, const float* __restrict__ W_hh1,
                const float* __restrict__ b_ih1, const float* __restrict__ b_hh1,
                const float* __restrict__ W_lin, const float* __restrict__ b_lin,
                float* __restrict__ out)
{
    const int tid = threadIdx.x;
    const int w = tid >> 6;          // wave 0..12 = tile m
    const int l = tid & 63;
    const int n = l & 15;            // column slot (0-3 real batch)
    const int p = l >> 4;            // lane group 0..3
    const int m = w;

    __shared__ _Float16 H0[2][1024];
    __shared__ _Float16 H1[2][1024];
    __shared__ __align__(16) float PRE[1632];   // 408 x f32x4 (both layers)
    __shared__ float XS[4][1032];               // staged x, padded rows

    for (int i = tid; i < 1024; i += NTH){
        H0[0][i] = (_Float16)0.f; H0[1][i] = (_Float16)0.f;
        H1[0][i] = (_Float16)0.f; H1[1][i] = (_Float16)0.f;
    }
    const long long bb = (long long)blockIdx.x * NBATCH;
    for (int i = tid; i < 4*TLEN; i += NTH){
        const int r = i >> 10, c = i & 1023;
        XS[r][c] = x[(bb + r)*TLEN + c];
    }

    // ---- GEMM-role: persistent fp16 weight fragments ----
    f16x8 A0[2];   // W_hh0, K=64
    f16x8 A1[4];   // [0..1]=W_ih1 (k<64), [2..3]=W_hh1 (k 64..127) + proj row 204
    {
        const int ar = 16*m + n;              // A-row = gate g = 4j + r
        const int aj = ar >> 2, arr = ar & 3;
        const bool rowv = (aj < HID);
        const int orow = arr*HID + aj;
        const float gsc = (arr == 2) ? 2.f*LOG2E : LOG2E;
        #pragma unroll
        for (int kb=0; kb<2; ++kb){
            f16x8 hi;
            #pragma unroll
            for (int jj=0; jj<8; ++jj){
                const int k = kb*32 + 8*p + jj;
                const float wv = (rowv && k < HID) ? gsc * W_hh0[orow*HID + k] : 0.f;
                hi[jj] = (_Float16)wv;
            }
            A0[kb] = hi;
        }
        #pragma unroll
        for (int kb=0; kb<4; ++kb){
            f16x8 hi;
            #pragma unroll
            for (int jj=0; jj<8; ++jj){
                const int k = kb*32 + 8*p + jj;   // 0..127: [h0 ; h1]
                float wv = 0.f;
                if (rowv){
                    if (k < 64) { if (k < HID) wv = gsc * W_ih1[orow*HID + k]; }
                    else        { const int kk = k - 64; if (kk < HID) wv = gsc * W_hh1[orow*HID + kk]; }
                } else if (ar == 204 && k >= 64){ // projection row (unscaled!)
                    const int kk = k - 64; if (kk < HID) wv = W_lin[kk];
                }
                hi[jj] = (_Float16)wv;
            }
            A1[kb] = hi;
        }
    }
    const int je = 4*m + p;
    const bool stA  = (n < NBATCH) && (je < HID);   // PRE store mask
    const bool outm = (w == 12) && (p == 3) && (n < NBATCH);
    const float blin = b_lin[0];

    // ---- epilogue-role: one chain per lane ----
    const int q = tid;
    const bool eact = (q < 408);
    const int lay = (q >= 204) ? 1 : 0;
    const int qq = q - lay*204;
    const int jq = qq >> 2, nq = qq & 3;
    f32x4 biasq = {0.f,0.f,0.f,0.f}, wxq = {0.f,0.f,0.f,0.f};
    if (eact){
        const float* bi = lay ? b_ih1 : b_ih0;
        const float* bh = lay ? b_hh1 : b_hh0;
        #pragma unroll
        for (int r4=0; r4<4; ++r4){
            const float gs4 = (r4 == 2) ? 2.f*LOG2E : LOG2E;
            const int oe = r4*HID + jq;
            biasq[r4] = gs4 * (bi[oe] + bh[oe]);
            if (!lay) wxq[r4] = gs4 * W_ih0[oe];
        }
    }
    const int widxq = ((jq>>5)<<9) + (nq + ((jq>>3)&3)*16)*8 + (jq&7);
    float cst = 0.f;    // cell state of this lane's (layer, unit, batch)

    __syncthreads();

    for (int s = 0; s <= TLEN + 1; ++s){
        const int pw = s & 1, pr = pw ^ 1;

        // ---------- phase A: GEMM (L0(s), L1(s-1)) + out(s-2) ----------
        f16x8 rb[2], r1[2];
        #pragma unroll
        for (int kb=0; kb<2; ++kb){
            rb[kb] = *reinterpret_cast<const f16x8*>(&H0[pr][kb*512 + l*8]);
            r1[kb] = *reinterpret_cast<const f16x8*>(&H1[pw][kb*512 + l*8]);
        }
        if (s < TLEN){
            f32x4 a = {0.f,0.f,0.f,0.f};
            __builtin_amdgcn_s_setprio(1);
            a = __builtin_amdgcn_mfma_f32_16x16x32_f16(A0[0], rb[0], a, 0,0,0);
            a = __builtin_amdgcn_mfma_f32_16x16x32_f16(A0[1], rb[1], a, 0,0,0);
            __builtin_amdgcn_s_setprio(0);
            if (stA) *reinterpret_cast<f32x4*>(&PRE[(je*4 + n)*4]) = a;
        }
        if (s >= 1){
            f32x4 b0 = {0.f,0.f,0.f,0.f}, b1 = {0.f,0.f,0.f,0.f};
            __builtin_amdgcn_s_setprio(1);
            b0 = __builtin_amdgcn_mfma_f32_16x16x32_f16(A1[0], rb[0], b0, 0,0,0);
            b0 = __builtin_amdgcn_mfma_f32_16x16x32_f16(A1[1], rb[1], b0, 0,0,0);
            b1 = __builtin_amdgcn_mfma_f32_16x16x32_f16(A1[2], r1[0], b1, 0,0,0);
            b1 = __builtin_amdgcn_mfma_f32_16x16x32_f16(A1[3], r1[1], b1, 0,0,0);
            __builtin_amdgcn_s_setprio(0);
            const f32x4 pre1 = b0 + b1;
            if (stA && s <= TLEN)
                *reinterpret_cast<f32x4*>(&PRE[(204 + je*4 + n)*4]) = pre1;
            if (outm && s >= 2)
                out[(bb + n)*TLEN + (s-2)] = pre1[0] + blin;   // proj row 204
        }
        __syncthreads();

        // ---------- phase B: epilogue chains (one per lane) ----------
        if (eact && (lay ? (s >= 1 && s <= TLEN) : (s < TLEN))){
            f32x4 pre = *reinterpret_cast<const f32x4*>(&PRE[q*4]);
            pre += biasq;
            if (!lay){
                const float xq = XS[nq][s];
                #pragma unroll
                for (int r4=0; r4<4; ++r4) pre[r4] = fmaf(xq, wxq[r4], pre[r4]);
            }
            const float gi = sigm2(pre[0]);
            const float gf = sigm2(pre[1]);
            const float gg = fmaf(2.f, sigm2(pre[2]), -1.f);
            const float go = sigm2(pre[3]);
            cst = fmaf(gf, cst, gi*gg);
            const float hv = go * tanh_c(cst);
            if (lay) H1[pr][widxq] = (_Float16)hv;   // h1(s-1)
            else     H0[pw][widxq] = (_Float16)hv;   // h0(s)
        }
        __syncthreads();
    }
}

extern "C" void kernel_launch(void* const* d_in, const int* in_sizes, int n_in,
                              void* d_out, int out_size, void* d_ws, size_t ws_size,
                              hipStream_t stream) {
    const float* x     = (const float*)d_in[0];
    const float* W_ih0 = (const float*)d_in[1];
    const float* W_hh0 = (const float*)d_in[2];
    const float* b_ih0 = (const float*)d_in[3];
    const float* b_hh0 = (const float*)d_in[4];
    const float* W_ih1 = (const float*)d_in[5];
    const float* W_hh1 = (const float*)d_in[6];
    const float* b_ih1 = (const float*)d_in[7];
    const float* b_hh1 = (const float*)d_in[8];
    const float* W_lin = (const float*)d_in[9];
    const float* b_lin = (const float*)d_in[10];
    float* out = (float*)d_out;

    const int B = in_sizes[0] / TLEN;
    lstm2_mfma<<<dim3(B / NBATCH), dim3(NTH), 0, stream>>>(
        x, W_ih0, W_hh0, b_ih0, b_hh0, W_ih1, W_hh1, b_ih1, b_hh1, W_lin, b_lin, out);
}